// Round 1
// baseline (118.043 us; speedup 1.0000x reference)
//
#include <hip/hip_runtime.h>

#define BSEG   64
#define LATENT 256
#define PAD    16   // floats per accumulator slot -> 64B, one cache line per segment

// Monotone order-preserving f32 -> u32 encoding (for atomicMax on floats).
__device__ __forceinline__ unsigned enc_f32(float x) {
    unsigned u = __float_as_uint(x);
    return (u & 0x80000000u) ? ~u : (u | 0x80000000u);
}
__device__ __forceinline__ float dec_f32(unsigned e) {
    unsigned u = (e & 0x80000000u) ? (e & 0x7FFFFFFFu) : ~e;
    return __uint_as_float(u);
}

// Kernel A: uncertainty[b] = sum_k 0.5*log(2*pi*e*std^2) = 128*log(2pi e) + sum log std
// Also (re-)initializes the global max/sum accumulators each call (graph-replay safe).
__global__ __launch_bounds__(256) void k_unc(const float* __restrict__ pstd,
                                             float* __restrict__ unc,
                                             unsigned* __restrict__ gmax,
                                             float* __restrict__ gsum,
                                             float* __restrict__ out_unc) {
    int b = blockIdx.x;
    float v = logf(pstd[b * LATENT + threadIdx.x]);
#pragma unroll
    for (int off = 32; off > 0; off >>= 1) v += __shfl_down(v, off, 64);
    __shared__ float part[4];
    int lane = threadIdx.x & 63, wv = threadIdx.x >> 6;
    if (lane == 0) part[wv] = v;
    __syncthreads();
    if (threadIdx.x == 0) {
        float s = part[0] + part[1] + part[2] + part[3];
        float u = 128.0f * 2.83787706640934548f + s;  // 128*log(2*pi*e) + sum(log std)
        unc[b]     = u;
        out_unc[b] = u;
        gmax[b * PAD] = 0u;    // enc(-inf) lower bound
        gsum[b * PAD] = 0.0f;
    }
}

// Kernel B: priority = coherence * unc[batch]; per-segment max via LDS atomics.
__global__ __launch_bounds__(256) void k_pri_max(const float* __restrict__ coh,
                                                 const int* __restrict__ batch,
                                                 const float* __restrict__ unc,
                                                 unsigned* __restrict__ gmax,
                                                 float* __restrict__ pri, int n) {
    __shared__ float    unc_s[BSEG];
    __shared__ unsigned max_s[BSEG];
    int t = threadIdx.x;
    if (t < BSEG) { unc_s[t] = unc[t]; max_s[t] = 0u; }
    __syncthreads();
    int gid = blockIdx.x * blockDim.x + t;
    int gstride = gridDim.x * blockDim.x;
    int nv = n >> 2;
    for (int i = gid; i < nv; i += gstride) {
        float4 cv = ((const float4*)coh)[i];
        int4   bv = ((const int4*)batch)[i];
        float p0 = cv.x * unc_s[bv.x];
        float p1 = cv.y * unc_s[bv.y];
        float p2 = cv.z * unc_s[bv.z];
        float p3 = cv.w * unc_s[bv.w];
        ((float4*)pri)[i] = make_float4(p0, p1, p2, p3);
        atomicMax(&max_s[bv.x], enc_f32(p0));
        atomicMax(&max_s[bv.y], enc_f32(p1));
        atomicMax(&max_s[bv.z], enc_f32(p2));
        atomicMax(&max_s[bv.w], enc_f32(p3));
    }
    for (int i = (nv << 2) + gid; i < n; i += gstride) {
        int b = batch[i];
        float p = coh[i] * unc_s[b];
        pri[i] = p;
        atomicMax(&max_s[b], enc_f32(p));
    }
    __syncthreads();
    if (t < BSEG) atomicMax(&gmax[t * PAD], max_s[t]);
}

// Kernel C: seg_sum[b] = sum exp(priority - seg_max[b])
__global__ __launch_bounds__(256) void k_sum(const float* __restrict__ pri,
                                             const int* __restrict__ batch,
                                             const unsigned* __restrict__ gmax,
                                             float* __restrict__ gsum, int n) {
    __shared__ float m_s[BSEG];
    __shared__ float sum_s[BSEG];
    int t = threadIdx.x;
    if (t < BSEG) { m_s[t] = dec_f32(gmax[t * PAD]); sum_s[t] = 0.0f; }
    __syncthreads();
    int gid = blockIdx.x * blockDim.x + t;
    int gstride = gridDim.x * blockDim.x;
    int nv = n >> 2;
    for (int i = gid; i < nv; i += gstride) {
        float4 pv = ((const float4*)pri)[i];
        int4   bv = ((const int4*)batch)[i];
        atomicAdd(&sum_s[bv.x], expf(pv.x - m_s[bv.x]));
        atomicAdd(&sum_s[bv.y], expf(pv.y - m_s[bv.y]));
        atomicAdd(&sum_s[bv.z], expf(pv.z - m_s[bv.z]));
        atomicAdd(&sum_s[bv.w], expf(pv.w - m_s[bv.w]));
    }
    for (int i = (nv << 2) + gid; i < n; i += gstride) {
        int b = batch[i];
        atomicAdd(&sum_s[b], expf(pri[i] - m_s[b]));
    }
    __syncthreads();
    if (t < BSEG) atomicAdd(&gsum[t * PAD], sum_s[t]);
}

// Kernel D: normalized = exp(priority - seg_max[b]) / seg_sum[b]
__global__ __launch_bounds__(256) void k_norm(const float* __restrict__ pri,
                                              const int* __restrict__ batch,
                                              const unsigned* __restrict__ gmax,
                                              const float* __restrict__ gsum,
                                              float* __restrict__ out_nrm, int n) {
    __shared__ float m_s[BSEG];
    __shared__ float r_s[BSEG];
    int t = threadIdx.x;
    if (t < BSEG) { m_s[t] = dec_f32(gmax[t * PAD]); r_s[t] = 1.0f / gsum[t * PAD]; }
    __syncthreads();
    int gid = blockIdx.x * blockDim.x + t;
    int gstride = gridDim.x * blockDim.x;
    int nv = n >> 2;
    for (int i = gid; i < nv; i += gstride) {
        float4 pv = ((const float4*)pri)[i];
        int4   bv = ((const int4*)batch)[i];
        float4 ov;
        ov.x = expf(pv.x - m_s[bv.x]) * r_s[bv.x];
        ov.y = expf(pv.y - m_s[bv.y]) * r_s[bv.y];
        ov.z = expf(pv.z - m_s[bv.z]) * r_s[bv.z];
        ov.w = expf(pv.w - m_s[bv.w]) * r_s[bv.w];
        ((float4*)out_nrm)[i] = ov;
    }
    for (int i = (nv << 2) + gid; i < n; i += gstride) {
        int b = batch[i];
        out_nrm[i] = expf(pri[i] - m_s[b]) * r_s[b];
    }
}

extern "C" void kernel_launch(void* const* d_in, const int* in_sizes, int n_in,
                              void* d_out, int out_size, void* d_ws, size_t ws_size,
                              hipStream_t stream) {
    const float* coh   = (const float*)d_in[0];
    // d_in[1] = posterior_mean (unused by the reference outputs)
    const float* pstd  = (const float*)d_in[2];
    const int*   batch = (const int*)d_in[3];
    int n = in_sizes[0];

    float* out     = (float*)d_out;
    float* out_pri = out;
    float* out_nrm = out + n;
    float* out_unc = out + 2 * (size_t)n;

    // ws layout: [0,256)B unc ; [256, 256+4096)B padded max(enc u32) ; then padded sum
    float*    ws_unc = (float*)d_ws;
    unsigned* ws_max = (unsigned*)((char*)d_ws + 256);
    float*    ws_sum = (float*)((char*)d_ws + 256 + BSEG * PAD * 4);

    k_unc<<<BSEG, 256, 0, stream>>>(pstd, ws_unc, ws_max, ws_sum, out_unc);

    int blocks = 2048;
    k_pri_max<<<blocks, 256, 0, stream>>>(coh, batch, ws_unc, ws_max, out_pri, n);
    k_sum<<<blocks, 256, 0, stream>>>(out_pri, batch, ws_max, ws_sum, n);
    k_norm<<<blocks, 256, 0, stream>>>(out_pri, batch, ws_max, ws_sum, out_nrm, n);
}

// Round 2
// 36.615 us; speedup vs baseline: 3.2239x; 3.2239x over previous
//
#include <hip/hip_runtime.h>

#define BSEG   64
#define LATENT 256
#define NB     1024            // blocks for the big streaming kernels
#define SCALE_F   1.0995116e12f         // 2^40 (e <= 1 after max subtraction)
#define INV_SCALE 9.094947017729282e-13 // 2^-40 (double)

// Monotone order-preserving f32 -> u32 encoding (for integer atomicMax on floats).
__device__ __forceinline__ unsigned enc_f32(float x) {
    unsigned u = __float_as_uint(x);
    return (u & 0x80000000u) ? ~u : (u | 0x80000000u);
}
__device__ __forceinline__ float dec_f32(unsigned e) {
    unsigned u = (e & 0x80000000u) ? (e & 0x7FFFFFFFu) : ~e;
    return __uint_as_float(u);
}

// A: uncertainty[b] = 128*log(2*pi*e) + sum_k log(std)
__global__ __launch_bounds__(256) void k_unc(const float* __restrict__ pstd,
                                             float* __restrict__ unc,
                                             float* __restrict__ out_unc) {
    int b = blockIdx.x;
    float v = logf(pstd[b * LATENT + threadIdx.x]);
#pragma unroll
    for (int off = 32; off > 0; off >>= 1) v += __shfl_down(v, off, 64);
    __shared__ float part[4];
    int lane = threadIdx.x & 63, wv = threadIdx.x >> 6;
    if (lane == 0) part[wv] = v;
    __syncthreads();
    if (threadIdx.x == 0) {
        float s = part[0] + part[1] + part[2] + part[3];
        float u = 128.0f * 2.83787706640934548f + s;
        unc[b]     = u;
        out_unc[b] = u;
    }
}

// B: priority = coherence * unc[batch]; per-wave LDS atomicMax (native u32);
//    block writes 64 partial maxima (no global atomics).
__global__ __launch_bounds__(256) void k_pri_max(const float* __restrict__ coh,
                                                 const int* __restrict__ batch,
                                                 const float* __restrict__ unc,
                                                 unsigned* __restrict__ pmax,
                                                 float* __restrict__ pri, int n) {
    __shared__ float    unc_s[BSEG];
    __shared__ unsigned max_s[4][BSEG];
    int t = threadIdx.x, wv = t >> 6;
    if (t < BSEG) {
        float u = unc[t];
        unc_s[t] = u;
        max_s[0][t] = 0u; max_s[1][t] = 0u; max_s[2][t] = 0u; max_s[3][t] = 0u;
    }
    __syncthreads();
    int gid = blockIdx.x * 256 + t;
    int gstride = NB * 256;
    int nv = n >> 2;
    for (int i = gid; i < nv; i += gstride) {
        float4 cv = ((const float4*)coh)[i];
        int4   bv = ((const int4*)batch)[i];
        float p0 = cv.x * unc_s[bv.x];
        float p1 = cv.y * unc_s[bv.y];
        float p2 = cv.z * unc_s[bv.z];
        float p3 = cv.w * unc_s[bv.w];
        ((float4*)pri)[i] = make_float4(p0, p1, p2, p3);
        atomicMax(&max_s[wv][bv.x], enc_f32(p0));
        atomicMax(&max_s[wv][bv.y], enc_f32(p1));
        atomicMax(&max_s[wv][bv.z], enc_f32(p2));
        atomicMax(&max_s[wv][bv.w], enc_f32(p3));
    }
    for (int i = (nv << 2) + gid; i < n; i += gstride) {
        int b = batch[i];
        float p = coh[i] * unc_s[b];
        pri[i] = p;
        atomicMax(&max_s[wv][b], enc_f32(p));
    }
    __syncthreads();
    if (t < BSEG) {
        unsigned m = max(max(max_s[0][t], max_s[1][t]), max(max_s[2][t], max_s[3][t]));
        pmax[blockIdx.x * BSEG + t] = m;
    }
}

// Reduce partial maxima -> final per-segment max (float).
__global__ __launch_bounds__(256) void k_redmax(const unsigned* __restrict__ pmax,
                                                float* __restrict__ maxf) {
    int s = blockIdx.x;
    unsigned m = 0u;
    for (int i = threadIdx.x; i < NB; i += 256) m = max(m, pmax[i * BSEG + s]);
#pragma unroll
    for (int off = 32; off > 0; off >>= 1) m = max(m, (unsigned)__shfl_down((int)m, off, 64));
    __shared__ unsigned part[4];
    int lane = threadIdx.x & 63, wv = threadIdx.x >> 6;
    if (lane == 0) part[wv] = m;
    __syncthreads();
    if (threadIdx.x == 0) {
        unsigned mm = max(max(part[0], part[1]), max(part[2], part[3]));
        maxf[s] = dec_f32(mm);
    }
}

// C: partial seg sums of exp(p - max) in fixed-point u64 via NATIVE LDS integer atomics.
__global__ __launch_bounds__(256) void k_sum(const float* __restrict__ pri,
                                             const int* __restrict__ batch,
                                             const float* __restrict__ maxf,
                                             float* __restrict__ psum, int n) {
    __shared__ float m_s[BSEG];
    __shared__ unsigned long long sum_s[4][BSEG];
    int t = threadIdx.x, wv = t >> 6;
    if (t < BSEG) {
        m_s[t] = maxf[t];
        sum_s[0][t] = 0ull; sum_s[1][t] = 0ull; sum_s[2][t] = 0ull; sum_s[3][t] = 0ull;
    }
    __syncthreads();
    int gid = blockIdx.x * 256 + t;
    int gstride = NB * 256;
    int nv = n >> 2;
    for (int i = gid; i < nv; i += gstride) {
        float4 pv = ((const float4*)pri)[i];
        int4   bv = ((const int4*)batch)[i];
        atomicAdd(&sum_s[wv][bv.x], (unsigned long long)(expf(pv.x - m_s[bv.x]) * SCALE_F));
        atomicAdd(&sum_s[wv][bv.y], (unsigned long long)(expf(pv.y - m_s[bv.y]) * SCALE_F));
        atomicAdd(&sum_s[wv][bv.z], (unsigned long long)(expf(pv.z - m_s[bv.z]) * SCALE_F));
        atomicAdd(&sum_s[wv][bv.w], (unsigned long long)(expf(pv.w - m_s[bv.w]) * SCALE_F));
    }
    for (int i = (nv << 2) + gid; i < n; i += gstride) {
        int b = batch[i];
        atomicAdd(&sum_s[wv][b], (unsigned long long)(expf(pri[i] - m_s[b]) * SCALE_F));
    }
    __syncthreads();
    if (t < BSEG) {
        unsigned long long tot = sum_s[0][t] + sum_s[1][t] + sum_s[2][t] + sum_s[3][t];
        psum[blockIdx.x * BSEG + t] = (float)((double)tot * INV_SCALE);
    }
}

// Reduce partial sums -> reciprocal of per-segment sum.
__global__ __launch_bounds__(256) void k_redsum(const float* __restrict__ psum,
                                                float* __restrict__ rsum) {
    int s = blockIdx.x;
    float v = 0.0f;
    for (int i = threadIdx.x; i < NB; i += 256) v += psum[i * BSEG + s];
#pragma unroll
    for (int off = 32; off > 0; off >>= 1) v += __shfl_down(v, off, 64);
    __shared__ float part[4];
    int lane = threadIdx.x & 63, wv = threadIdx.x >> 6;
    if (lane == 0) part[wv] = v;
    __syncthreads();
    if (threadIdx.x == 0) {
        float s4 = part[0] + part[1] + part[2] + part[3];
        rsum[s] = 1.0f / s4;
    }
}

// D: normalized = exp(priority - max[b]) * rsum[b]
__global__ __launch_bounds__(256) void k_norm(const float* __restrict__ pri,
                                              const int* __restrict__ batch,
                                              const float* __restrict__ maxf,
                                              const float* __restrict__ rsum,
                                              float* __restrict__ out_nrm, int n) {
    __shared__ float m_s[BSEG];
    __shared__ float r_s[BSEG];
    int t = threadIdx.x;
    if (t < BSEG) { m_s[t] = maxf[t]; r_s[t] = rsum[t]; }
    __syncthreads();
    int gid = blockIdx.x * 256 + t;
    int gstride = NB * 256;
    int nv = n >> 2;
    for (int i = gid; i < nv; i += gstride) {
        float4 pv = ((const float4*)pri)[i];
        int4   bv = ((const int4*)batch)[i];
        float4 ov;
        ov.x = expf(pv.x - m_s[bv.x]) * r_s[bv.x];
        ov.y = expf(pv.y - m_s[bv.y]) * r_s[bv.y];
        ov.z = expf(pv.z - m_s[bv.z]) * r_s[bv.z];
        ov.w = expf(pv.w - m_s[bv.w]) * r_s[bv.w];
        ((float4*)out_nrm)[i] = ov;
    }
    for (int i = (nv << 2) + gid; i < n; i += gstride) {
        int b = batch[i];
        out_nrm[i] = expf(pri[i] - m_s[b]) * r_s[b];
    }
}

extern "C" void kernel_launch(void* const* d_in, const int* in_sizes, int n_in,
                              void* d_out, int out_size, void* d_ws, size_t ws_size,
                              hipStream_t stream) {
    const float* coh   = (const float*)d_in[0];
    // d_in[1] = posterior_mean (unused by the reference outputs)
    const float* pstd  = (const float*)d_in[2];
    const int*   batch = (const int*)d_in[3];
    int n = in_sizes[0];

    float* out     = (float*)d_out;
    float* out_pri = out;
    float* out_nrm = out + n;
    float* out_unc = out + 2 * (size_t)n;

    // ws layout (bytes):
    // [0,256)    unc
    // [256,512)  maxf
    // [512,768)  rsum
    // [1024, 1024+NB*64*4)                 pmax (u32 partial maxima)
    // [1024+NB*64*4, 1024+2*NB*64*4)       psum (f32 partial sums)
    float*    ws_unc  = (float*)d_ws;
    float*    ws_maxf = (float*)((char*)d_ws + 256);
    float*    ws_rsum = (float*)((char*)d_ws + 512);
    unsigned* ws_pmax = (unsigned*)((char*)d_ws + 1024);
    float*    ws_psum = (float*)((char*)d_ws + 1024 + NB * BSEG * 4);

    k_unc    <<<BSEG, 256, 0, stream>>>(pstd, ws_unc, out_unc);
    k_pri_max<<<NB,   256, 0, stream>>>(coh, batch, ws_unc, ws_pmax, out_pri, n);
    k_redmax <<<BSEG, 256, 0, stream>>>(ws_pmax, ws_maxf);
    k_sum    <<<NB,   256, 0, stream>>>(out_pri, batch, ws_maxf, ws_psum, n);
    k_redsum <<<BSEG, 256, 0, stream>>>(ws_psum, ws_rsum);
    k_norm   <<<NB,   256, 0, stream>>>(out_pri, batch, ws_maxf, ws_rsum, out_nrm, n);
}